// Round 16
// baseline (355.971 us; speedup 1.0000x reference)
//
#include <hip/hip_runtime.h>

// Neurcomp / SIREN MLP inference — round 22: r21 + WH-into-S2 overlap (h staging
// writes ride inside the mm2 MFMA stream; next-layer weight PF moved into S2).
// r21 post-mortem: steady main 289us (MfmaUtil 44.3), official 342 — gap is
// harness/prep overhead. Combined issue 84.6%; occupancy locked at 2 waves/SIMD
// by the UNIFIED reg file (~220 live V+A vs 256 @2w / 170 @3w) — LDS-shrink
// can't unlock 3 waves; structural escapes exhausted (r9/r12/r13/r17).
// Remaining exposed serial phase: layer-top h staging (16 ds_write_b128 + drain
// + 16 reads + PK8). WH(·,nt) only needs H finalized by S2(nt), and the buffer
// rows are dead during mm2 (s1 reads complete before S2(0)) -> move the 16
// WH writes into S2(t) (after the H update), and the next layer's mm1-t0 PF
// between S2(6) and S2(7). Layer-top becomes RS x8 only. Prologue does layer-0
// WH + PF; final-layer WH writes are dead/harmless. Zero numeric change:
// absmax must read exactly 4.8828e-4.
// Layouts (learn_hip m89/m120, r6/r8-verified): A[m=lane&15][k=(lane>>4)*8+j],
// B[k=(lane>>4)*8+j][n=lane&15], D row=(lane>>4)*4+reg, col=lane&15.

typedef unsigned int u32;
typedef short s8v __attribute__((ext_vector_type(8)));   // 8 bf16 (bits)
typedef float f4v __attribute__((ext_vector_type(4)));
typedef u32   u4v __attribute__((ext_vector_type(4)));

constexpr float OMEGA = 30.0f;
constexpr float KREV = 4.7746482946f;  // OMEGA / (2*pi)
constexpr int HID = 128, NRES = 7, BT = 256;
constexpr int WROW = 136;              // dwords per LDS row: 32 b128-blocks + pad
constexpr int WAVE_LDS = 32 * WROW;    // 4352 dwords per wave (32 rows)
constexpr int FRAG_ELEMS = 14 * 16384; // bf16 elems per hi/lo ws array

__device__ __forceinline__ float sin_om(float z) {      // first layer only
    float r = z * (OMEGA * 0.15915494309189535f);
    return __builtin_amdgcn_sinf(__builtin_amdgcn_fractf(r));
}
__device__ __forceinline__ float sinrev(float r) {      // input in revolutions
    return __builtin_amdgcn_sinf(__builtin_amdgcn_fractf(r));
}
__device__ __forceinline__ f4v mfma16(s8v a, s8v b, f4v c) {
    return __builtin_amdgcn_mfma_f32_16x16x32_bf16(a, b, c, 0, 0, 0);
}
__device__ __forceinline__ u32 fu(float f) { return __builtin_bit_cast(u32, f); }
__device__ __forceinline__ float andf(float f) {
    return __builtin_bit_cast(float, __builtin_bit_cast(u32, f) & 0xffff0000u);
}
__device__ __forceinline__ s8v bc(u4v v) { return __builtin_bit_cast(s8v, v); }

// 8 fp32 (frag elem order j=0..7) -> hi s8v + lo s8v (truncation split).
// v_perm sel 0x07060302: D = {a.hi16 (top), b.hi16 (low)}.
#define PK8(e0,e1,e2,e3,e4,e5,e6,e7, FH_, FL_) { \
    u4v h_, l_; \
    h_.x = __builtin_amdgcn_perm(fu(e1), fu(e0), 0x07060302u); \
    h_.y = __builtin_amdgcn_perm(fu(e3), fu(e2), 0x07060302u); \
    h_.z = __builtin_amdgcn_perm(fu(e5), fu(e4), 0x07060302u); \
    h_.w = __builtin_amdgcn_perm(fu(e7), fu(e6), 0x07060302u); \
    float L0_ = e0 - andf(e0), L1_ = e1 - andf(e1); \
    float L2_ = e2 - andf(e2), L3_ = e3 - andf(e3); \
    float L4_ = e4 - andf(e4), L5_ = e5 - andf(e5); \
    float L6_ = e6 - andf(e6), L7_ = e7 - andf(e7); \
    l_.x = __builtin_amdgcn_perm(fu(L1_), fu(L0_), 0x07060302u); \
    l_.y = __builtin_amdgcn_perm(fu(L3_), fu(L2_), 0x07060302u); \
    l_.z = __builtin_amdgcn_perm(fu(L5_), fu(L4_), 0x07060302u); \
    l_.w = __builtin_amdgcn_perm(fu(L7_), fu(L6_), 0x07060302u); \
    FH_ = __builtin_bit_cast(s8v, h_); FL_ = __builtin_bit_cast(s8v, l_); }

// h (D-layout regs, feature 16nt+4q+reg at point-row) -> LDS, b128 swizzled.
#define WH(mt,nt) { \
    f4v hv_; hv_.x = H_##mt##_##nt##_0; hv_.y = H_##mt##_##nt##_1; \
    hv_.z = H_##mt##_##nt##_2; hv_.w = H_##mt##_##nt##_3; \
    *(f4v*)&buf[(mt ? rowbase1 : rowbase0) + ((((nt)*4 + q) ^ lnk) << 2)] = hv_; }

// LDS -> B-fragments, split-on-read.
#define RS(mt,kc) { \
    const int rb_ = mt ? rowbase1 : rowbase0; \
    f4v u_ = *(const f4v*)&buf[rb_ + ((((kc)*8 + q*2    ) ^ lnk) << 2)]; \
    f4v v_ = *(const f4v*)&buf[rb_ + ((((kc)*8 + q*2 + 1) ^ lnk) << 2)]; \
    PK8(u_.x, u_.y, u_.z, u_.w, v_.x, v_.y, v_.z, v_.w, FH##mt##kc, FL##mt##kc) }

// prefetch weight tile + pre-scaled bias into buffer S — PURE LOADS ONLY.
#define PF(S, fbv, bp) { \
    g##S##0 = whi[fbv]; g##S##1 = whi[(fbv)+64]; \
    g##S##2 = whi[(fbv)+128]; g##S##3 = whi[(fbv)+192]; \
    r##S##0 = wlo[fbv]; r##S##1 = wlo[(fbv)+64]; \
    r##S##2 = wlo[(fbv)+128]; r##S##3 = wlo[(fbv)+192]; \
    cv##S = *(const f4v*)(bp); }

// 24 MFMAs consuming buffer S — FOUR independent chains, round-robin (r16),
// wrapped in s_setprio(1)/(0) (T5, kept from r20).
#define MMB4(S) { \
    s8v h0_=bc(g##S##0), l0_=bc(r##S##0), h1_=bc(g##S##1), l1_=bc(r##S##1); \
    s8v h2_=bc(g##S##2), l2_=bc(r##S##2), h3_=bc(g##S##3), l3_=bc(r##S##3); \
    __builtin_amdgcn_s_setprio(1); \
    c0  = mfma16(h0_, FH00, c0 ); c1  = mfma16(h0_, FH10, c1 ); \
    c0b = mfma16(h2_, FH02, c0b); c1b = mfma16(h2_, FH12, c1b); \
    c0  = mfma16(h0_, FL00, c0 ); c1  = mfma16(h0_, FL10, c1 ); \
    c0b = mfma16(h2_, FL02, c0b); c1b = mfma16(h2_, FL12, c1b); \
    c0  = mfma16(l0_, FH00, c0 ); c1  = mfma16(l0_, FH10, c1 ); \
    c0b = mfma16(l2_, FH02, c0b); c1b = mfma16(l2_, FH12, c1b); \
    c0  = mfma16(h1_, FH01, c0 ); c1  = mfma16(h1_, FH11, c1 ); \
    c0b = mfma16(h3_, FH03, c0b); c1b = mfma16(h3_, FH13, c1b); \
    c0  = mfma16(h1_, FL01, c0 ); c1  = mfma16(h1_, FL11, c1 ); \
    c0b = mfma16(h3_, FL03, c0b); c1b = mfma16(h3_, FL13, c1b); \
    c0  = mfma16(l1_, FH01, c0 ); c1  = mfma16(l1_, FH11, c1 ); \
    c0b = mfma16(l3_, FH03, c0b); c1b = mfma16(l3_, FH13, c1b); \
    __builtin_amdgcn_s_setprio(0); \
    c0 += c0b; c1 += c1b; }

// mm1 step t consuming buffer S: s1 = sin(acc_rev), staged to LDS
#define S1(t, S) { \
    f4v c0 = cv##S; f4v c1 = c0; \
    f4v c0b = {0.f, 0.f, 0.f, 0.f}; f4v c1b = c0b; \
    MMB4(S) \
    f4v s0v, s1v; \
    s0v.x = sinrev(c0.x); s0v.y = sinrev(c0.y); \
    s0v.z = sinrev(c0.z); s0v.w = sinrev(c0.w); \
    s1v.x = sinrev(c1.x); s1v.y = sinrev(c1.y); \
    s1v.z = sinrev(c1.z); s1v.w = sinrev(c1.w); \
    const int bo_ = (((t)*4 + q) ^ lnk) << 2; \
    *(f4v*)&buf[rowbase0 + bo_] = s0v; \
    *(f4v*)&buf[rowbase1 + bo_] = s1v; }

// mm2 step t consuming buffer S: epilogue h += s2, then stage h' for the NEXT
// layer's mm1 (WH rides inside the mm2 MFMA stream; buffer rows are dead here).
#define S2W(t, S) { \
    f4v c0 = cv##S; f4v c1 = c0; \
    f4v c0b = {0.f, 0.f, 0.f, 0.f}; f4v c1b = c0b; \
    MMB4(S) \
    H_0_##t##_0 += sinrev(c0.x); H_0_##t##_1 += sinrev(c0.y); \
    H_0_##t##_2 += sinrev(c0.z); H_0_##t##_3 += sinrev(c0.w); \
    H_1_##t##_0 += sinrev(c1.x); H_1_##t##_1 += sinrev(c1.y); \
    H_1_##t##_2 += sinrev(c1.z); H_1_##t##_3 += sinrev(c1.w); \
    WH(0,t) WH(1,t) }

// ---- repetition lists ----
#define LNT8(M) M(0) M(1) M(2) M(3) M(4) M(5) M(6) M(7)
#define LW16(M) M(0,0) M(0,1) M(0,2) M(0,3) M(0,4) M(0,5) M(0,6) M(0,7) \
                M(1,0) M(1,1) M(1,2) M(1,3) M(1,4) M(1,5) M(1,6) M(1,7)
#define LH64(M) \
  M(0,0,0) M(0,0,1) M(0,0,2) M(0,0,3) M(0,1,0) M(0,1,1) M(0,1,2) M(0,1,3) \
  M(0,2,0) M(0,2,1) M(0,2,2) M(0,2,3) M(0,3,0) M(0,3,1) M(0,3,2) M(0,3,3) \
  M(0,4,0) M(0,4,1) M(0,4,2) M(0,4,3) M(0,5,0) M(0,5,1) M(0,5,2) M(0,5,3) \
  M(0,6,0) M(0,6,1) M(0,6,2) M(0,6,3) M(0,7,0) M(0,7,1) M(0,7,2) M(0,7,3) \
  M(1,0,0) M(1,0,1) M(1,0,2) M(1,0,3) M(1,1,0) M(1,1,1) M(1,1,2) M(1,1,3) \
  M(1,2,0) M(1,2,1) M(1,2,2) M(1,2,3) M(1,3,0) M(1,3,1) M(1,3,2) M(1,3,3) \
  M(1,4,0) M(1,4,1) M(1,4,2) M(1,4,3) M(1,5,0) M(1,5,1) M(1,5,2) M(1,5,3) \
  M(1,6,0) M(1,6,1) M(1,6,2) M(1,6,3) M(1,7,0) M(1,7,1) M(1,7,2) M(1,7,3)

#define DH(mt,nt,reg) float H_##mt##_##nt##_##reg;

// first layer (unscaled w0 -> sin_om keeps the omega multiply)
#define F0(nt) { \
    f4v wa_ = *(const f4v*)(w0p + nt*48 + q*12); \
    f4v wb_ = *(const f4v*)(w0p + nt*48 + q*12 + 4); \
    f4v wc_ = *(const f4v*)(w0p + nt*48 + q*12 + 8); \
    f4v bb_ = *(const f4v*)(b0p + nt*16 + q4); \
    H_0_##nt##_0 = sin_om(fmaf(wa_.x, X0, fmaf(wa_.y, Y0, fmaf(wa_.z, Z0, bb_.x)))); \
    H_0_##nt##_1 = sin_om(fmaf(wa_.w, X0, fmaf(wb_.x, Y0, fmaf(wb_.y, Z0, bb_.y)))); \
    H_0_##nt##_2 = sin_om(fmaf(wb_.z, X0, fmaf(wb_.w, Y0, fmaf(wc_.x, Z0, bb_.z)))); \
    H_0_##nt##_3 = sin_om(fmaf(wc_.y, X0, fmaf(wc_.z, Y0, fmaf(wc_.w, Z0, bb_.w)))); \
    H_1_##nt##_0 = sin_om(fmaf(wa_.x, X1, fmaf(wa_.y, Y1, fmaf(wa_.z, Z1, bb_.x)))); \
    H_1_##nt##_1 = sin_om(fmaf(wa_.w, X1, fmaf(wb_.x, Y1, fmaf(wb_.y, Z1, bb_.y)))); \
    H_1_##nt##_2 = sin_om(fmaf(wb_.z, X1, fmaf(wb_.w, Y1, fmaf(wc_.x, Z1, bb_.z)))); \
    H_1_##nt##_3 = sin_om(fmaf(wc_.y, X1, fmaf(wc_.z, Y1, fmaf(wc_.w, Z1, bb_.w)))); }

// final head partials
#define HF(nt) { f4v wf_ = *(const f4v*)(wfp + nt*16 + q4); \
    P0 = fmaf(wf_.x, H_0_##nt##_0, fmaf(wf_.y, H_0_##nt##_1, \
         fmaf(wf_.z, H_0_##nt##_2, fmaf(wf_.w, H_0_##nt##_3, P0)))); \
    P1 = fmaf(wf_.x, H_1_##nt##_0, fmaf(wf_.y, H_1_##nt##_1, \
         fmaf(wf_.z, H_1_##nt##_2, fmaf(wf_.w, H_1_##nt##_3, P1)))); }

// ---- weight prep: 1 element/thread, coalesced (r21, unchanged).
__global__ void prep_kernel(const float* __restrict__ rw1,
                            const float* __restrict__ rw2,
                            const float* __restrict__ rb1,
                            const float* __restrict__ rb2,
                            unsigned short* __restrict__ wsHi,
                            unsigned short* __restrict__ wsLo,
                            float* __restrict__ wsBias) {
    int e = blockIdx.x * 256 + threadIdx.x;       // 0 .. 229375
    int j = e & 7, lane = (e >> 3) & 63, kc = (e >> 9) & 3;
    int t = (e >> 11) & 7, L = e >> 14;
    int i = L >> 1;
    bool isW1 = ((L & 1) == 0);
    const float* W = (isW1 ? rw1 : rw2) + i * HID * HID;
    float sc = ((isW1 && i > 0) ? 0.5f : 1.0f) * KREV;   // wgt1 + omega/2pi fold
    int n = t * 16 + (lane & 15);                  // output feature
    int k0 = kc * 32 + (lane >> 4) * 8;            // input feature base
    float w = W[n * HID + k0 + j] * sc;
    u32 b = __builtin_bit_cast(u32, w);
    u32 hb = b & 0xffff0000u;
    float lo = w - __builtin_bit_cast(float, hb);
    wsHi[e] = (unsigned short)(b >> 16);
    wsLo[e] = (unsigned short)(__builtin_bit_cast(u32, lo) >> 16);
    if (e < 14 * HID) {                            // scaled biases: layer Lb, feat f
        int Lb = e >> 7, f = e & 127;
        int li = Lb >> 1;
        float bv = ((Lb & 1) == 0 ? rb1[li * HID + f] : rb2[li * HID + f]);
        wsBias[e] = bv * KREV;
    }
}

__global__ void __launch_bounds__(BT)
__attribute__((amdgpu_waves_per_eu(2, 2)))
siren_mfma(const float* __restrict__ x,
           const float* __restrict__ w0p, const float* __restrict__ b0p,
           const float* __restrict__ bwp,      // pre-scaled biases (d_ws tail)
           const float* __restrict__ wfp, const float* __restrict__ bfp,
           const u4v* __restrict__ whi, const u4v* __restrict__ wlo,
           float* __restrict__ out, int NP)
{
    __shared__ float buf[4 * WAVE_LDS];            // 69632 B, wave-private staging

    const int tid = threadIdx.x;
    const int wv = tid >> 6, lane = tid & 63;
    const int ln = lane & 15, q = lane >> 4;
    const int q4 = q * 4;
    const int lnk = ln & 7;                        // LDS XOR-swizzle key (per row)
    const int rowbase0 = wv * WAVE_LDS + ln * WROW;        // mt0 row (point = ln)
    const int rowbase1 = rowbase0 + 16 * WROW;             // mt1 row (point = 16+ln)
    const int base_pt = blockIdx.x * 128 + wv * 32;

    // ---- first SineLayer, feature-major H
    LH64(DH)
    {
        int p0_ = base_pt + ln;      int i0_ = p0_ < NP ? p0_ : NP - 1;
        int p1_ = base_pt + 16 + ln; int i1_ = p1_ < NP ? p1_ : NP - 1;
        float X0 = x[3*i0_], Y0 = x[3*i0_+1], Z0 = x[3*i0_+2];
        float X1 = x[3*i1_], Y1 = x[3*i1_+1], Z1 = x[3*i1_+2];
        LNT8(F0)
    }

    // activation B-fragments (hi/lo) for 2 point-tiles x 4 k-chunks
    s8v FH00, FH01, FH02, FH03, FH10, FH11, FH12, FH13;
    s8v FL00, FL01, FL02, FL03, FL10, FL11, FL12, FL13;

    // ping-pong prefetch buffers
    u4v ga0, ga1, ga2, ga3, ra0, ra1, ra2, ra3;
    u4v gb0, gb1, gb2, gb3, rb0, rb1, rb2, rb3;
    f4v cva, cvb;

    // ---- prologue: stage layer-0 h to LDS + prefetch mm1-t0 of layer 0
    PF(a, lane, bwp + q4)
    LW16(WH)

    for (int i = 0; i < NRES; ++i) {
        const int fb1 = (2*i) * 2048 + lane, fb2 = (2*i+1) * 2048 + lane;
        const float* __restrict__ B1l = bwp + (2*i) * HID;
        const float* __restrict__ B2l = bwp + (2*i+1) * HID;
        const int inx = (i < NRES - 1) ? i + 1 : 0;           // next layer (wrap: dead)
        const int fb1n = (2*inx) * 2048 + lane;
        const float* __restrict__ B1n = bwp + (2*inx) * HID;

        // h -> B-fragments (writes were staged during the previous mm2 / prologue)
        RS(0,0) RS(0,1) RS(0,2) RS(0,3)
        RS(1,0) RS(1,1) RS(1,2) RS(1,3)

        // ---- matmul1 -> s1, software-pipelined (prefetch t+1 before consume t)
        PF(b, fb1 + 256,  B1l + 16 + q4)   S1(0, a)
        PF(a, fb1 + 512,  B1l + 32 + q4)   S1(1, b)
        PF(b, fb1 + 768,  B1l + 48 + q4)   S1(2, a)
        PF(a, fb1 + 1024, B1l + 64 + q4)   S1(3, b)
        PF(b, fb1 + 1280, B1l + 80 + q4)   S1(4, a)
        PF(a, fb1 + 1536, B1l + 96 + q4)   S1(5, b)
        PF(b, fb1 + 1792, B1l + 112 + q4)  S1(6, a)
        PF(a, fb2,        B2l + q4)        S1(7, b)   // prefetch mm2-t0

        // s1 -> fragments (split-on-read)
        RS(0,0) RS(0,1) RS(0,2) RS(0,3)
        RS(1,0) RS(1,1) RS(1,2) RS(1,3)

        // ---- matmul2 -> s2; epilogue h += s2, h' staged to LDS inside the stream
        PF(b, fb2 + 256,  B2l + 16 + q4)   S2W(0, a)
        PF(a, fb2 + 512,  B2l + 32 + q4)   S2W(1, b)
        PF(b, fb2 + 768,  B2l + 48 + q4)   S2W(2, a)
        PF(a, fb2 + 1024, B2l + 64 + q4)   S2W(3, b)
        PF(b, fb2 + 1280, B2l + 80 + q4)   S2W(4, a)
        PF(a, fb2 + 1536, B2l + 96 + q4)   S2W(5, b)
        PF(b, fb2 + 1792, B2l + 112 + q4)  S2W(6, a)
        PF(a, fb1n,       B1n + q4)        S2W(7, b)  // prefetch NEXT layer mm1-t0
    }

    // ---- final linear head
    float P0 = 0.f, P1 = 0.f;
    LNT8(HF)
    P0 += __shfl_xor(P0, 16); P0 += __shfl_xor(P0, 32);
    P1 += __shfl_xor(P1, 16); P1 += __shfl_xor(P1, 32);
    const float bf0 = bfp[0];
    if (q == 0) {
        int p0_ = base_pt + ln;
        if (p0_ < NP) out[p0_] = fmaf(P0, 0.5f, bf0);      // 0.5 = last-layer wgt2
        int p1_ = base_pt + 16 + ln;
        if (p1_ < NP) out[p1_] = fmaf(P1, 0.5f, bf0);
    }
}

extern "C" void kernel_launch(void* const* d_in, const int* in_sizes, int n_in,
                              void* d_out, int out_size, void* d_ws, size_t ws_size,
                              hipStream_t stream) {
    const float* x   = (const float*)d_in[0];
    const float* w0  = (const float*)d_in[1];
    const float* b0  = (const float*)d_in[2];
    const float* rw1 = (const float*)d_in[3];
    const float* rb1 = (const float*)d_in[4];
    const float* rw2 = (const float*)d_in[5];
    const float* rb2 = (const float*)d_in[6];
    const float* wf  = (const float*)d_in[7];
    const float* bf  = (const float*)d_in[8];
    float* out = (float*)d_out;

    unsigned short* wsHi = (unsigned short*)d_ws;          // 458752 B
    unsigned short* wsLo = wsHi + FRAG_ELEMS;              // 458752 B
    float* wsBias = (float*)(wsLo + FRAG_ELEMS);           // 7168 B (total 924672)

    const int n = in_sizes[0] / 3;                          // 200000
    prep_kernel<<<896, 256, 0, stream>>>(rw1, rw2, rb1, rb2, wsHi, wsLo, wsBias);
    const int grid = (n + 127) / 128;
    siren_mfma<<<grid, BT, 0, stream>>>(x, w0, b0, wsBias, wf, bf,
                                        (const u4v*)wsHi, (const u4v*)wsLo,
                                        out, n);
}

// Round 17
// 263.975 us; speedup vs baseline: 1.3485x; 1.3485x over previous
//
#include <hip/hip_runtime.h>

// Neurcomp / SIREN MLP inference — round 23: r21 base + 2-term MFMA (RTN bf16
// weights, activation hi/lo split kept).
// r22 post-mortem: WH-into-S2 regressed (289->293.5 steady) — layer-top phase
// was already partner-covered. Reverted to r21.
// r21 state: MFMA busy 127us (3-term pipe floor), VALU 116us, issue 84.6%,
// all scheduling/occupancy levers exhausted. absmax pinned at 2^-11 for 11
// rounds (sin-approx dominated; split contribution ~2^-17) vs 3.2e-3 threshold
// -> 6.5x slack. Change the FLOOR: drop the Wl*Hh term. Weights quantized to
// single bf16 with round-to-nearest-even in prep (fp32, free, unbiased);
// activations stay split (exact). Error: fixed dW perturbation rel 2^-9 ->
// per-matmul phase err ~1-2.5e-4 rev; head contraction (sqrt(128)*wf*0.5 ~
// 0.024 rms attenuation) -> predicted output absmax ~5-9e-4 << 3.2e-3.
// Gains: MFMA/t-block 24->16 (floor 127->85us), weight traffic + PF loads
// halved (8->4 u4v), ping-pong buffers shed 32 regs. All else identical r21.
// Layouts (learn_hip m89/m120, r6/r8-verified): A[m=lane&15][k=(lane>>4)*8+j],
// B[k=(lane>>4)*8+j][n=lane&15], D row=(lane>>4)*4+reg, col=lane&15.

typedef unsigned int u32;
typedef short s8v __attribute__((ext_vector_type(8)));   // 8 bf16 (bits)
typedef float f4v __attribute__((ext_vector_type(4)));
typedef u32   u4v __attribute__((ext_vector_type(4)));

constexpr float OMEGA = 30.0f;
constexpr float KREV = 4.7746482946f;  // OMEGA / (2*pi)
constexpr int HID = 128, NRES = 7, BT = 256;
constexpr int WROW = 136;              // dwords per LDS row: 32 b128-blocks + pad
constexpr int WAVE_LDS = 32 * WROW;    // 4352 dwords per wave (32 rows)
constexpr int FRAG_ELEMS = 14 * 16384; // bf16 elems in the weight-frag array

__device__ __forceinline__ float sin_om(float z) {      // first layer only
    float r = z * (OMEGA * 0.15915494309189535f);
    return __builtin_amdgcn_sinf(__builtin_amdgcn_fractf(r));
}
__device__ __forceinline__ float sinrev(float r) {      // input in revolutions
    return __builtin_amdgcn_sinf(__builtin_amdgcn_fractf(r));
}
__device__ __forceinline__ f4v mfma16(s8v a, s8v b, f4v c) {
    return __builtin_amdgcn_mfma_f32_16x16x32_bf16(a, b, c, 0, 0, 0);
}
__device__ __forceinline__ u32 fu(float f) { return __builtin_bit_cast(u32, f); }
__device__ __forceinline__ float andf(float f) {
    return __builtin_bit_cast(float, __builtin_bit_cast(u32, f) & 0xffff0000u);
}
__device__ __forceinline__ s8v bc(u4v v) { return __builtin_bit_cast(s8v, v); }

// 8 fp32 (frag elem order j=0..7) -> hi s8v + lo s8v (truncation split; the
// activation side keeps full hi/lo precision, exact to ~2^-17).
#define PK8(e0,e1,e2,e3,e4,e5,e6,e7, FH_, FL_) { \
    u4v h_, l_; \
    h_.x = __builtin_amdgcn_perm(fu(e1), fu(e0), 0x07060302u); \
    h_.y = __builtin_amdgcn_perm(fu(e3), fu(e2), 0x07060302u); \
    h_.z = __builtin_amdgcn_perm(fu(e5), fu(e4), 0x07060302u); \
    h_.w = __builtin_amdgcn_perm(fu(e7), fu(e6), 0x07060302u); \
    float L0_ = e0 - andf(e0), L1_ = e1 - andf(e1); \
    float L2_ = e2 - andf(e2), L3_ = e3 - andf(e3); \
    float L4_ = e4 - andf(e4), L5_ = e5 - andf(e5); \
    float L6_ = e6 - andf(e6), L7_ = e7 - andf(e7); \
    l_.x = __builtin_amdgcn_perm(fu(L1_), fu(L0_), 0x07060302u); \
    l_.y = __builtin_amdgcn_perm(fu(L3_), fu(L2_), 0x07060302u); \
    l_.z = __builtin_amdgcn_perm(fu(L5_), fu(L4_), 0x07060302u); \
    l_.w = __builtin_amdgcn_perm(fu(L7_), fu(L6_), 0x07060302u); \
    FH_ = __builtin_bit_cast(s8v, h_); FL_ = __builtin_bit_cast(s8v, l_); }

// h (D-layout regs, feature 16nt+4q+reg at point-row) -> LDS, b128 swizzled.
#define WH(mt,nt) { \
    f4v hv_; hv_.x = H_##mt##_##nt##_0; hv_.y = H_##mt##_##nt##_1; \
    hv_.z = H_##mt##_##nt##_2; hv_.w = H_##mt##_##nt##_3; \
    *(f4v*)&buf[(mt ? rowbase1 : rowbase0) + ((((nt)*4 + q) ^ lnk) << 2)] = hv_; }

// LDS -> B-fragments, split-on-read.
#define RS(mt,kc) { \
    const int rb_ = mt ? rowbase1 : rowbase0; \
    f4v u_ = *(const f4v*)&buf[rb_ + ((((kc)*8 + q*2    ) ^ lnk) << 2)]; \
    f4v v_ = *(const f4v*)&buf[rb_ + ((((kc)*8 + q*2 + 1) ^ lnk) << 2)]; \
    PK8(u_.x, u_.y, u_.z, u_.w, v_.x, v_.y, v_.z, v_.w, FH##mt##kc, FL##mt##kc) }

// prefetch weight tile (RTN bf16, single array) + pre-scaled bias — pure loads.
#define PF(S, fbv, bp) { \
    g##S##0 = whi[fbv]; g##S##1 = whi[(fbv)+64]; \
    g##S##2 = whi[(fbv)+128]; g##S##3 = whi[(fbv)+192]; \
    cv##S = *(const f4v*)(bp); }

// 16 MFMAs consuming buffer S — FOUR independent chains, round-robin, with
// s_setprio around the cluster (T5, kept). Terms per kc: Wb*Hh, Wb*Hl.
#define MMB4(S) { \
    s8v h0_=bc(g##S##0), h1_=bc(g##S##1), h2_=bc(g##S##2), h3_=bc(g##S##3); \
    __builtin_amdgcn_s_setprio(1); \
    c0  = mfma16(h0_, FH00, c0 ); c1  = mfma16(h0_, FH10, c1 ); \
    c0b = mfma16(h2_, FH02, c0b); c1b = mfma16(h2_, FH12, c1b); \
    c0  = mfma16(h0_, FL00, c0 ); c1  = mfma16(h0_, FL10, c1 ); \
    c0b = mfma16(h2_, FL02, c0b); c1b = mfma16(h2_, FL12, c1b); \
    c0  = mfma16(h1_, FH01, c0 ); c1  = mfma16(h1_, FH11, c1 ); \
    c0b = mfma16(h3_, FH03, c0b); c1b = mfma16(h3_, FH13, c1b); \
    c0  = mfma16(h1_, FL01, c0 ); c1  = mfma16(h1_, FL11, c1 ); \
    c0b = mfma16(h3_, FL03, c0b); c1b = mfma16(h3_, FL13, c1b); \
    __builtin_amdgcn_s_setprio(0); \
    c0 += c0b; c1 += c1b; }

// mm1 step t consuming buffer S: s1 = sin(acc_rev), staged to LDS
#define S1(t, S) { \
    f4v c0 = cv##S; f4v c1 = c0; \
    f4v c0b = {0.f, 0.f, 0.f, 0.f}; f4v c1b = c0b; \
    MMB4(S) \
    f4v s0v, s1v; \
    s0v.x = sinrev(c0.x); s0v.y = sinrev(c0.y); \
    s0v.z = sinrev(c0.z); s0v.w = sinrev(c0.w); \
    s1v.x = sinrev(c1.x); s1v.y = sinrev(c1.y); \
    s1v.z = sinrev(c1.z); s1v.w = sinrev(c1.w); \
    const int bo_ = (((t)*4 + q) ^ lnk) << 2; \
    *(f4v*)&buf[rowbase0 + bo_] = s0v; \
    *(f4v*)&buf[rowbase1 + bo_] = s1v; }

// mm2 step t consuming buffer S: epilogue h += s2 (last-layer 0.5 in head)
#define S2(t, S) { \
    f4v c0 = cv##S; f4v c1 = c0; \
    f4v c0b = {0.f, 0.f, 0.f, 0.f}; f4v c1b = c0b; \
    MMB4(S) \
    H_0_##t##_0 += sinrev(c0.x); H_0_##t##_1 += sinrev(c0.y); \
    H_0_##t##_2 += sinrev(c0.z); H_0_##t##_3 += sinrev(c0.w); \
    H_1_##t##_0 += sinrev(c1.x); H_1_##t##_1 += sinrev(c1.y); \
    H_1_##t##_2 += sinrev(c1.z); H_1_##t##_3 += sinrev(c1.w); }

// ---- repetition lists ----
#define LNT8(M) M(0) M(1) M(2) M(3) M(4) M(5) M(6) M(7)
#define LW16(M) M(0,0) M(0,1) M(0,2) M(0,3) M(0,4) M(0,5) M(0,6) M(0,7) \
                M(1,0) M(1,1) M(1,2) M(1,3) M(1,4) M(1,5) M(1,6) M(1,7)
#define LH64(M) \
  M(0,0,0) M(0,0,1) M(0,0,2) M(0,0,3) M(0,1,0) M(0,1,1) M(0,1,2) M(0,1,3) \
  M(0,2,0) M(0,2,1) M(0,2,2) M(0,2,3) M(0,3,0) M(0,3,1) M(0,3,2) M(0,3,3) \
  M(0,4,0) M(0,4,1) M(0,4,2) M(0,4,3) M(0,5,0) M(0,5,1) M(0,5,2) M(0,5,3) \
  M(0,6,0) M(0,6,1) M(0,6,2) M(0,6,3) M(0,7,0) M(0,7,1) M(0,7,2) M(0,7,3) \
  M(1,0,0) M(1,0,1) M(1,0,2) M(1,0,3) M(1,1,0) M(1,1,1) M(1,1,2) M(1,1,3) \
  M(1,2,0) M(1,2,1) M(1,2,2) M(1,2,3) M(1,3,0) M(1,3,1) M(1,3,2) M(1,3,3) \
  M(1,4,0) M(1,4,1) M(1,4,2) M(1,4,3) M(1,5,0) M(1,5,1) M(1,5,2) M(1,5,3) \
  M(1,6,0) M(1,6,1) M(1,6,2) M(1,6,3) M(1,7,0) M(1,7,1) M(1,7,2) M(1,7,3)

#define DH(mt,nt,reg) float H_##mt##_##nt##_##reg;

// first layer (unscaled w0 -> sin_om keeps the omega multiply)
#define F0(nt) { \
    f4v wa_ = *(const f4v*)(w0p + nt*48 + q*12); \
    f4v wb_ = *(const f4v*)(w0p + nt*48 + q*12 + 4); \
    f4v wc_ = *(const f4v*)(w0p + nt*48 + q*12 + 8); \
    f4v bb_ = *(const f4v*)(b0p + nt*16 + q4); \
    H_0_##nt##_0 = sin_om(fmaf(wa_.x, X0, fmaf(wa_.y, Y0, fmaf(wa_.z, Z0, bb_.x)))); \
    H_0_##nt##_1 = sin_om(fmaf(wa_.w, X0, fmaf(wb_.x, Y0, fmaf(wb_.y, Z0, bb_.y)))); \
    H_0_##nt##_2 = sin_om(fmaf(wb_.z, X0, fmaf(wb_.w, Y0, fmaf(wc_.x, Z0, bb_.z)))); \
    H_0_##nt##_3 = sin_om(fmaf(wc_.y, X0, fmaf(wc_.z, Y0, fmaf(wc_.w, Z0, bb_.w)))); \
    H_1_##nt##_0 = sin_om(fmaf(wa_.x, X1, fmaf(wa_.y, Y1, fmaf(wa_.z, Z1, bb_.x)))); \
    H_1_##nt##_1 = sin_om(fmaf(wa_.w, X1, fmaf(wb_.x, Y1, fmaf(wb_.y, Z1, bb_.y)))); \
    H_1_##nt##_2 = sin_om(fmaf(wb_.z, X1, fmaf(wb_.w, Y1, fmaf(wc_.x, Z1, bb_.z)))); \
    H_1_##nt##_3 = sin_om(fmaf(wc_.y, X1, fmaf(wc_.z, Y1, fmaf(wc_.w, Z1, bb_.w)))); }

// final head partials
#define HF(nt) { f4v wf_ = *(const f4v*)(wfp + nt*16 + q4); \
    P0 = fmaf(wf_.x, H_0_##nt##_0, fmaf(wf_.y, H_0_##nt##_1, \
         fmaf(wf_.z, H_0_##nt##_2, fmaf(wf_.w, H_0_##nt##_3, P0)))); \
    P1 = fmaf(wf_.x, H_1_##nt##_0, fmaf(wf_.y, H_1_##nt##_1, \
         fmaf(wf_.z, H_1_##nt##_2, fmaf(wf_.w, H_1_##nt##_3, P1)))); }

// ---- weight prep: 1 element/thread, coalesced; RTN-even bf16 (single array)
// + KREV-scaled bias tail. Layout unchanged (e = [L|t|kc|lane|j]).
__global__ void prep_kernel(const float* __restrict__ rw1,
                            const float* __restrict__ rw2,
                            const float* __restrict__ rb1,
                            const float* __restrict__ rb2,
                            unsigned short* __restrict__ wsHi,
                            float* __restrict__ wsBias) {
    int e = blockIdx.x * 256 + threadIdx.x;       // 0 .. 229375
    int j = e & 7, lane = (e >> 3) & 63, kc = (e >> 9) & 3;
    int t = (e >> 11) & 7, L = e >> 14;
    int i = L >> 1;
    bool isW1 = ((L & 1) == 0);
    const float* W = (isW1 ? rw1 : rw2) + i * HID * HID;
    float sc = ((isW1 && i > 0) ? 0.5f : 1.0f) * KREV;   // wgt1 + omega/2pi fold
    int n = t * 16 + (lane & 15);                  // output feature
    int k0 = kc * 32 + (lane >> 4) * 8;            // input feature base
    float w = W[n * HID + k0 + j] * sc;
    u32 b = __builtin_bit_cast(u32, w);
    u32 r = b + 0x7fffu + ((b >> 16) & 1u);        // round-to-nearest-even bf16
    wsHi[e] = (unsigned short)(r >> 16);
    if (e < 14 * HID) {                            // scaled biases: layer Lb, feat f
        int Lb = e >> 7, f = e & 127;
        int li = Lb >> 1;
        float bv = ((Lb & 1) == 0 ? rb1[li * HID + f] : rb2[li * HID + f]);
        wsBias[e] = bv * KREV;
    }
}

__global__ void __launch_bounds__(BT)
__attribute__((amdgpu_waves_per_eu(2, 2)))
siren_mfma(const float* __restrict__ x,
           const float* __restrict__ w0p, const float* __restrict__ b0p,
           const float* __restrict__ bwp,      // pre-scaled biases (d_ws tail)
           const float* __restrict__ wfp, const float* __restrict__ bfp,
           const u4v* __restrict__ whi,
           float* __restrict__ out, int NP)
{
    __shared__ float buf[4 * WAVE_LDS];            // 69632 B, wave-private staging

    const int tid = threadIdx.x;
    const int wv = tid >> 6, lane = tid & 63;
    const int ln = lane & 15, q = lane >> 4;
    const int q4 = q * 4;
    const int lnk = ln & 7;                        // LDS XOR-swizzle key (per row)
    const int rowbase0 = wv * WAVE_LDS + ln * WROW;        // mt0 row (point = ln)
    const int rowbase1 = rowbase0 + 16 * WROW;             // mt1 row (point = 16+ln)
    const int base_pt = blockIdx.x * 128 + wv * 32;

    // ---- first SineLayer, feature-major H
    LH64(DH)
    {
        int p0_ = base_pt + ln;      int i0_ = p0_ < NP ? p0_ : NP - 1;
        int p1_ = base_pt + 16 + ln; int i1_ = p1_ < NP ? p1_ : NP - 1;
        float X0 = x[3*i0_], Y0 = x[3*i0_+1], Z0 = x[3*i0_+2];
        float X1 = x[3*i1_], Y1 = x[3*i1_+1], Z1 = x[3*i1_+2];
        LNT8(F0)
    }

    // activation B-fragments (hi/lo) for 2 point-tiles x 4 k-chunks
    s8v FH00, FH01, FH02, FH03, FH10, FH11, FH12, FH13;
    s8v FL00, FL01, FL02, FL03, FL10, FL11, FL12, FL13;

    // ping-pong prefetch buffers (weights now single bf16: 4 u4v each)
    u4v ga0, ga1, ga2, ga3;
    u4v gb0, gb1, gb2, gb3;
    f4v cva, cvb;

    for (int i = 0; i < NRES; ++i) {
        const int fb1 = (2*i) * 2048 + lane, fb2 = (2*i+1) * 2048 + lane;
        const float* __restrict__ B1l = bwp + (2*i) * HID;
        const float* __restrict__ B2l = bwp + (2*i+1) * HID;

        // prefetch mm1-t0 while the h transpose phase runs
        PF(a, fb1, B1l + q4)

        // h (D-layout) -> LDS -> B-fragments (swizzled b128 round-trip)
        LW16(WH)
        RS(0,0) RS(0,1) RS(0,2) RS(0,3)
        RS(1,0) RS(1,1) RS(1,2) RS(1,3)

        // ---- matmul1 -> s1, software-pipelined (prefetch t+1 before consume t)
        PF(b, fb1 + 256,  B1l + 16 + q4)   S1(0, a)
        PF(a, fb1 + 512,  B1l + 32 + q4)   S1(1, b)
        PF(b, fb1 + 768,  B1l + 48 + q4)   S1(2, a)
        PF(a, fb1 + 1024, B1l + 64 + q4)   S1(3, b)
        PF(b, fb1 + 1280, B1l + 80 + q4)   S1(4, a)
        PF(a, fb1 + 1536, B1l + 96 + q4)   S1(5, b)
        PF(b, fb1 + 1792, B1l + 112 + q4)  S1(6, a)
        PF(a, fb2,        B2l + q4)        S1(7, b)   // prefetch mm2-t0

        // s1 -> fragments (split-on-read)
        RS(0,0) RS(0,1) RS(0,2) RS(0,3)
        RS(1,0) RS(1,1) RS(1,2) RS(1,3)

        // ---- matmul2 -> s2; epilogue h += s2
        PF(b, fb2 + 256,  B2l + 16 + q4)   S2(0, a)
        PF(a, fb2 + 512,  B2l + 32 + q4)   S2(1, b)
        PF(b, fb2 + 768,  B2l + 48 + q4)   S2(2, a)
        PF(a, fb2 + 1024, B2l + 64 + q4)   S2(3, b)
        PF(b, fb2 + 1280, B2l + 80 + q4)   S2(4, a)
        PF(a, fb2 + 1536, B2l + 96 + q4)   S2(5, b)
        PF(b, fb2 + 1792, B2l + 112 + q4)  S2(6, a)
        S2(7, b)
    }

    // ---- final linear head
    float P0 = 0.f, P1 = 0.f;
    LNT8(HF)
    P0 += __shfl_xor(P0, 16); P0 += __shfl_xor(P0, 32);
    P1 += __shfl_xor(P1, 16); P1 += __shfl_xor(P1, 32);
    const float bf0 = bfp[0];
    if (q == 0) {
        int p0_ = base_pt + ln;
        if (p0_ < NP) out[p0_] = fmaf(P0, 0.5f, bf0);      // 0.5 = last-layer wgt2
        int p1_ = base_pt + 16 + ln;
        if (p1_ < NP) out[p1_] = fmaf(P1, 0.5f, bf0);
    }
}

extern "C" void kernel_launch(void* const* d_in, const int* in_sizes, int n_in,
                              void* d_out, int out_size, void* d_ws, size_t ws_size,
                              hipStream_t stream) {
    const float* x   = (const float*)d_in[0];
    const float* w0  = (const float*)d_in[1];
    const float* b0  = (const float*)d_in[2];
    const float* rw1 = (const float*)d_in[3];
    const float* rb1 = (const float*)d_in[4];
    const float* rw2 = (const float*)d_in[5];
    const float* rb2 = (const float*)d_in[6];
    const float* wf  = (const float*)d_in[7];
    const float* bf  = (const float*)d_in[8];
    float* out = (float*)d_out;

    unsigned short* wsHi = (unsigned short*)d_ws;          // 458752 B
    float* wsBias = (float*)(wsHi + FRAG_ELEMS);           // 7168 B (total 465920)

    const int n = in_sizes[0] / 3;                          // 200000
    prep_kernel<<<896, 256, 0, stream>>>(rw1, rw2, rb1, rb2, wsHi, wsBias);
    const int grid = (n + 127) / 128;
    siren_mfma<<<grid, BT, 0, stream>>>(x, w0, b0, wsBias, wf, bf,
                                        (const u4v*)wsHi, out, n);
}

// Round 18
// 205.369 us; speedup vs baseline: 1.7333x; 1.2854x over previous
//
#include <hip/hip_runtime.h>

// Neurcomp / SIREN MLP inference — round 24: r23 + drop activation-lo term
// (single-bf16 x single-bf16 MFMA, RTN both sides via v_cvt_pk_bf16_f32).
// r23 post-mortem: 2-term worked exactly as modeled (official 342->264, steady
// 289->215, absmax 9.77e-4 = predicted quadrature add of rel-2^-9 weight RTN).
// Now VALU is the pole again (47% = 101us vs MFMA 84us). Same lever, one more
// notch: drop Wb*Hl. Activations RTN'd to bf16 at pack time with
// v_cvt_pk_bf16_f32 (HW-verified on MI355X, T12/m214v22 recipe) — 4 instrs
// per fragment vs 16-op hi/lo split -> VALU pole drops too; MFMA/t-block
// 16->8 (floor 84->~42us). Error: activation RTN is the same rel-2^-9 class
// as the weight RTN that added ~8.5e-4 -> predicted absmax ~1.3-1.6e-3,
// 2x under the 3.2e-3 threshold (tripwire).
// All else identical to r23 (ping-pong PF, 4-chain round-robin, setprio,
// fp32 LDS staging, prescaled bias, coalesced prep).
// Layouts (learn_hip m89/m120, r6/r8-verified): A[m=lane&15][k=(lane>>4)*8+j],
// B[k=(lane>>4)*8+j][n=lane&15], D row=(lane>>4)*4+reg, col=lane&15.

typedef unsigned int u32;
typedef short s8v __attribute__((ext_vector_type(8)));   // 8 bf16 (bits)
typedef float f4v __attribute__((ext_vector_type(4)));
typedef u32   u4v __attribute__((ext_vector_type(4)));

constexpr float OMEGA = 30.0f;
constexpr float KREV = 4.7746482946f;  // OMEGA / (2*pi)
constexpr int HID = 128, NRES = 7, BT = 256;
constexpr int WROW = 136;              // dwords per LDS row: 32 b128-blocks + pad
constexpr int WAVE_LDS = 32 * WROW;    // 4352 dwords per wave (32 rows)
constexpr int FRAG_ELEMS = 14 * 16384; // bf16 elems in the weight-frag array

__device__ __forceinline__ float sin_om(float z) {      // first layer only
    float r = z * (OMEGA * 0.15915494309189535f);
    return __builtin_amdgcn_sinf(__builtin_amdgcn_fractf(r));
}
__device__ __forceinline__ float sinrev(float r) {      // input in revolutions
    return __builtin_amdgcn_sinf(__builtin_amdgcn_fractf(r));
}
__device__ __forceinline__ f4v mfma16(s8v a, s8v b, f4v c) {
    return __builtin_amdgcn_mfma_f32_16x16x32_bf16(a, b, c, 0, 0, 0);
}
__device__ __forceinline__ u32 fu(float f) { return __builtin_bit_cast(u32, f); }
__device__ __forceinline__ s8v bc(u4v v) { return __builtin_bit_cast(s8v, v); }
// RTN pack: low16 = bf16(a), high16 = bf16(b)  (v_cvt_pk_bf16_f32, T12 recipe)
__device__ __forceinline__ u32 pkrtn(float a, float b) {
    u32 r;
    asm("v_cvt_pk_bf16_f32 %0, %1, %2" : "=v"(r) : "v"(a), "v"(b));
    return r;
}

// 8 fp32 (frag elem order j=0..7) -> single bf16 s8v via RTN (4 cvt_pk).
#define PKH(e0,e1,e2,e3,e4,e5,e6,e7, FH_) { \
    u4v h_; \
    h_.x = pkrtn(e0, e1); \
    h_.y = pkrtn(e2, e3); \
    h_.z = pkrtn(e4, e5); \
    h_.w = pkrtn(e6, e7); \
    FH_ = __builtin_bit_cast(s8v, h_); }

// h (D-layout regs, feature 16nt+4q+reg at point-row) -> LDS, b128 swizzled.
#define WH(mt,nt) { \
    f4v hv_; hv_.x = H_##mt##_##nt##_0; hv_.y = H_##mt##_##nt##_1; \
    hv_.z = H_##mt##_##nt##_2; hv_.w = H_##mt##_##nt##_3; \
    *(f4v*)&buf[(mt ? rowbase1 : rowbase0) + ((((nt)*4 + q) ^ lnk) << 2)] = hv_; }

// LDS -> B-fragment (single bf16, RTN on read).
#define RS(mt,kc) { \
    const int rb_ = mt ? rowbase1 : rowbase0; \
    f4v u_ = *(const f4v*)&buf[rb_ + ((((kc)*8 + q*2    ) ^ lnk) << 2)]; \
    f4v v_ = *(const f4v*)&buf[rb_ + ((((kc)*8 + q*2 + 1) ^ lnk) << 2)]; \
    PKH(u_.x, u_.y, u_.z, u_.w, v_.x, v_.y, v_.z, v_.w, FH##mt##kc) }

// prefetch weight tile (RTN bf16, single array) + pre-scaled bias — pure loads.
#define PF(S, fbv, bp) { \
    g##S##0 = whi[fbv]; g##S##1 = whi[(fbv)+64]; \
    g##S##2 = whi[(fbv)+128]; g##S##3 = whi[(fbv)+192]; \
    cv##S = *(const f4v*)(bp); }

// 8 MFMAs consuming buffer S — FOUR independent chains (2 each), round-robin,
// s_setprio around the cluster (T5). One term per kc: Wb*Hb.
#define MMB4(S) { \
    s8v h0_=bc(g##S##0), h1_=bc(g##S##1), h2_=bc(g##S##2), h3_=bc(g##S##3); \
    __builtin_amdgcn_s_setprio(1); \
    c0  = mfma16(h0_, FH00, c0 ); c1  = mfma16(h0_, FH10, c1 ); \
    c0b = mfma16(h2_, FH02, c0b); c1b = mfma16(h2_, FH12, c1b); \
    c0  = mfma16(h1_, FH01, c0 ); c1  = mfma16(h1_, FH11, c1 ); \
    c0b = mfma16(h3_, FH03, c0b); c1b = mfma16(h3_, FH13, c1b); \
    __builtin_amdgcn_s_setprio(0); \
    c0 += c0b; c1 += c1b; }

// mm1 step t consuming buffer S: s1 = sin(acc_rev), staged to LDS
#define S1(t, S) { \
    f4v c0 = cv##S; f4v c1 = c0; \
    f4v c0b = {0.f, 0.f, 0.f, 0.f}; f4v c1b = c0b; \
    MMB4(S) \
    f4v s0v, s1v; \
    s0v.x = sinrev(c0.x); s0v.y = sinrev(c0.y); \
    s0v.z = sinrev(c0.z); s0v.w = sinrev(c0.w); \
    s1v.x = sinrev(c1.x); s1v.y = sinrev(c1.y); \
    s1v.z = sinrev(c1.z); s1v.w = sinrev(c1.w); \
    const int bo_ = (((t)*4 + q) ^ lnk) << 2; \
    *(f4v*)&buf[rowbase0 + bo_] = s0v; \
    *(f4v*)&buf[rowbase1 + bo_] = s1v; }

// mm2 step t consuming buffer S: epilogue h += s2 (last-layer 0.5 in head)
#define S2(t, S) { \
    f4v c0 = cv##S; f4v c1 = c0; \
    f4v c0b = {0.f, 0.f, 0.f, 0.f}; f4v c1b = c0b; \
    MMB4(S) \
    H_0_##t##_0 += sinrev(c0.x); H_0_##t##_1 += sinrev(c0.y); \
    H_0_##t##_2 += sinrev(c0.z); H_0_##t##_3 += sinrev(c0.w); \
    H_1_##t##_0 += sinrev(c1.x); H_1_##t##_1 += sinrev(c1.y); \
    H_1_##t##_2 += sinrev(c1.z); H_1_##t##_3 += sinrev(c1.w); }

// ---- repetition lists ----
#define LNT8(M) M(0) M(1) M(2) M(3) M(4) M(5) M(6) M(7)
#define LW16(M) M(0,0) M(0,1) M(0,2) M(0,3) M(0,4) M(0,5) M(0,6) M(0,7) \
                M(1,0) M(1,1) M(1,2) M(1,3) M(1,4) M(1,5) M(1,6) M(1,7)
#define LH64(M) \
  M(0,0,0) M(0,0,1) M(0,0,2) M(0,0,3) M(0,1,0) M(0,1,1) M(0,1,2) M(0,1,3) \
  M(0,2,0) M(0,2,1) M(0,2,2) M(0,2,3) M(0,3,0) M(0,3,1) M(0,3,2) M(0,3,3) \
  M(0,4,0) M(0,4,1) M(0,4,2) M(0,4,3) M(0,5,0) M(0,5,1) M(0,5,2) M(0,5,3) \
  M(0,6,0) M(0,6,1) M(0,6,2) M(0,6,3) M(0,7,0) M(0,7,1) M(0,7,2) M(0,7,3) \
  M(1,0,0) M(1,0,1) M(1,0,2) M(1,0,3) M(1,1,0) M(1,1,1) M(1,1,2) M(1,1,3) \
  M(1,2,0) M(1,2,1) M(1,2,2) M(1,2,3) M(1,3,0) M(1,3,1) M(1,3,2) M(1,3,3) \
  M(1,4,0) M(1,4,1) M(1,4,2) M(1,4,3) M(1,5,0) M(1,5,1) M(1,5,2) M(1,5,3) \
  M(1,6,0) M(1,6,1) M(1,6,2) M(1,6,3) M(1,7,0) M(1,7,1) M(1,7,2) M(1,7,3)

#define DH(mt,nt,reg) float H_##mt##_##nt##_##reg;

// first layer (unscaled w0 -> sin_om keeps the omega multiply)
#define F0(nt) { \
    f4v wa_ = *(const f4v*)(w0p + nt*48 + q*12); \
    f4v wb_ = *(const f4v*)(w0p + nt*48 + q*12 + 4); \
    f4v wc_ = *(const f4v*)(w0p + nt*48 + q*12 + 8); \
    f4v bb_ = *(const f4v*)(b0p + nt*16 + q4); \
    H_0_##nt##_0 = sin_om(fmaf(wa_.x, X0, fmaf(wa_.y, Y0, fmaf(wa_.z, Z0, bb_.x)))); \
    H_0_##nt##_1 = sin_om(fmaf(wa_.w, X0, fmaf(wb_.x, Y0, fmaf(wb_.y, Z0, bb_.y)))); \
    H_0_##nt##_2 = sin_om(fmaf(wb_.z, X0, fmaf(wb_.w, Y0, fmaf(wc_.x, Z0, bb_.z)))); \
    H_0_##nt##_3 = sin_om(fmaf(wc_.y, X0, fmaf(wc_.z, Y0, fmaf(wc_.w, Z0, bb_.w)))); \
    H_1_##nt##_0 = sin_om(fmaf(wa_.x, X1, fmaf(wa_.y, Y1, fmaf(wa_.z, Z1, bb_.x)))); \
    H_1_##nt##_1 = sin_om(fmaf(wa_.w, X1, fmaf(wb_.x, Y1, fmaf(wb_.y, Z1, bb_.y)))); \
    H_1_##nt##_2 = sin_om(fmaf(wb_.z, X1, fmaf(wb_.w, Y1, fmaf(wc_.x, Z1, bb_.z)))); \
    H_1_##nt##_3 = sin_om(fmaf(wc_.y, X1, fmaf(wc_.z, Y1, fmaf(wc_.w, Z1, bb_.w)))); }

// final head partials
#define HF(nt) { f4v wf_ = *(const f4v*)(wfp + nt*16 + q4); \
    P0 = fmaf(wf_.x, H_0_##nt##_0, fmaf(wf_.y, H_0_##nt##_1, \
         fmaf(wf_.z, H_0_##nt##_2, fmaf(wf_.w, H_0_##nt##_3, P0)))); \
    P1 = fmaf(wf_.x, H_1_##nt##_0, fmaf(wf_.y, H_1_##nt##_1, \
         fmaf(wf_.z, H_1_##nt##_2, fmaf(wf_.w, H_1_##nt##_3, P1)))); }

// ---- weight prep: 1 element/thread, coalesced; RTN-even bf16 (single array)
// + KREV-scaled bias tail (unchanged from r23).
__global__ void prep_kernel(const float* __restrict__ rw1,
                            const float* __restrict__ rw2,
                            const float* __restrict__ rb1,
                            const float* __restrict__ rb2,
                            unsigned short* __restrict__ wsHi,
                            float* __restrict__ wsBias) {
    int e = blockIdx.x * 256 + threadIdx.x;       // 0 .. 229375
    int j = e & 7, lane = (e >> 3) & 63, kc = (e >> 9) & 3;
    int t = (e >> 11) & 7, L = e >> 14;
    int i = L >> 1;
    bool isW1 = ((L & 1) == 0);
    const float* W = (isW1 ? rw1 : rw2) + i * HID * HID;
    float sc = ((isW1 && i > 0) ? 0.5f : 1.0f) * KREV;   // wgt1 + omega/2pi fold
    int n = t * 16 + (lane & 15);                  // output feature
    int k0 = kc * 32 + (lane >> 4) * 8;            // input feature base
    float w = W[n * HID + k0 + j] * sc;
    u32 b = __builtin_bit_cast(u32, w);
    u32 r = b + 0x7fffu + ((b >> 16) & 1u);        // round-to-nearest-even bf16
    wsHi[e] = (unsigned short)(r >> 16);
    if (e < 14 * HID) {                            // scaled biases: layer Lb, feat f
        int Lb = e >> 7, f = e & 127;
        int li = Lb >> 1;
        float bv = ((Lb & 1) == 0 ? rb1[li * HID + f] : rb2[li * HID + f]);
        wsBias[e] = bv * KREV;
    }
}

__global__ void __launch_bounds__(BT)
__attribute__((amdgpu_waves_per_eu(2, 2)))
siren_mfma(const float* __restrict__ x,
           const float* __restrict__ w0p, const float* __restrict__ b0p,
           const float* __restrict__ bwp,      // pre-scaled biases (d_ws tail)
           const float* __restrict__ wfp, const float* __restrict__ bfp,
           const u4v* __restrict__ whi,
           float* __restrict__ out, int NP)
{
    __shared__ float buf[4 * WAVE_LDS];            // 69632 B, wave-private staging

    const int tid = threadIdx.x;
    const int wv = tid >> 6, lane = tid & 63;
    const int ln = lane & 15, q = lane >> 4;
    const int q4 = q * 4;
    const int lnk = ln & 7;                        // LDS XOR-swizzle key (per row)
    const int rowbase0 = wv * WAVE_LDS + ln * WROW;        // mt0 row (point = ln)
    const int rowbase1 = rowbase0 + 16 * WROW;             // mt1 row (point = 16+ln)
    const int base_pt = blockIdx.x * 128 + wv * 32;

    // ---- first SineLayer, feature-major H
    LH64(DH)
    {
        int p0_ = base_pt + ln;      int i0_ = p0_ < NP ? p0_ : NP - 1;
        int p1_ = base_pt + 16 + ln; int i1_ = p1_ < NP ? p1_ : NP - 1;
        float X0 = x[3*i0_], Y0 = x[3*i0_+1], Z0 = x[3*i0_+2];
        float X1 = x[3*i1_], Y1 = x[3*i1_+1], Z1 = x[3*i1_+2];
        LNT8(F0)
    }

    // activation B-fragments (single bf16) for 2 point-tiles x 4 k-chunks
    s8v FH00, FH01, FH02, FH03, FH10, FH11, FH12, FH13;

    // ping-pong prefetch buffers (weights single bf16: 4 u4v each)
    u4v ga0, ga1, ga2, ga3;
    u4v gb0, gb1, gb2, gb3;
    f4v cva, cvb;

    for (int i = 0; i < NRES; ++i) {
        const int fb1 = (2*i) * 2048 + lane, fb2 = (2*i+1) * 2048 + lane;
        const float* __restrict__ B1l = bwp + (2*i) * HID;
        const float* __restrict__ B2l = bwp + (2*i+1) * HID;

        // prefetch mm1-t0 while the h transpose phase runs
        PF(a, fb1, B1l + q4)

        // h (D-layout) -> LDS -> B-fragments (swizzled b128 round-trip)
        LW16(WH)
        RS(0,0) RS(0,1) RS(0,2) RS(0,3)
        RS(1,0) RS(1,1) RS(1,2) RS(1,3)

        // ---- matmul1 -> s1, software-pipelined (prefetch t+1 before consume t)
        PF(b, fb1 + 256,  B1l + 16 + q4)   S1(0, a)
        PF(a, fb1 + 512,  B1l + 32 + q4)   S1(1, b)
        PF(b, fb1 + 768,  B1l + 48 + q4)   S1(2, a)
        PF(a, fb1 + 1024, B1l + 64 + q4)   S1(3, b)
        PF(b, fb1 + 1280, B1l + 80 + q4)   S1(4, a)
        PF(a, fb1 + 1536, B1l + 96 + q4)   S1(5, b)
        PF(b, fb1 + 1792, B1l + 112 + q4)  S1(6, a)
        PF(a, fb2,        B2l + q4)        S1(7, b)   // prefetch mm2-t0

        // s1 -> fragments (RTN on read)
        RS(0,0) RS(0,1) RS(0,2) RS(0,3)
        RS(1,0) RS(1,1) RS(1,2) RS(1,3)

        // ---- matmul2 -> s2; epilogue h += s2
        PF(b, fb2 + 256,  B2l + 16 + q4)   S2(0, a)
        PF(a, fb2 + 512,  B2l + 32 + q4)   S2(1, b)
        PF(b, fb2 + 768,  B2l + 48 + q4)   S2(2, a)
        PF(a, fb2 + 1024, B2l + 64 + q4)   S2(3, b)
        PF(b, fb2 + 1280, B2l + 80 + q4)   S2(4, a)
        PF(a, fb2 + 1536, B2l + 96 + q4)   S2(5, b)
        PF(b, fb2 + 1792, B2l + 112 + q4)  S2(6, a)
        S2(7, b)
    }

    // ---- final linear head
    float P0 = 0.f, P1 = 0.f;
    LNT8(HF)
    P0 += __shfl_xor(P0, 16); P0 += __shfl_xor(P0, 32);
    P1 += __shfl_xor(P1, 16); P1 += __shfl_xor(P1, 32);
    const float bf0 = bfp[0];
    if (q == 0) {
        int p0_ = base_pt + ln;
        if (p0_ < NP) out[p0_] = fmaf(P0, 0.5f, bf0);      // 0.5 = last-layer wgt2
        int p1_ = base_pt + 16 + ln;
        if (p1_ < NP) out[p1_] = fmaf(P1, 0.5f, bf0);
    }
}

extern "C" void kernel_launch(void* const* d_in, const int* in_sizes, int n_in,
                              void* d_out, int out_size, void* d_ws, size_t ws_size,
                              hipStream_t stream) {
    const float* x   = (const float*)d_in[0];
    const float* w0  = (const float*)d_in[1];
    const float* b0  = (const float*)d_in[2];
    const float* rw1 = (const float*)d_in[3];
    const float* rb1 = (const float*)d_in[4];
    const float* rw2 = (const float*)d_in[5];
    const float* rb2 = (const float*)d_in[6];
    const float* wf  = (const float*)d_in[7];
    const float* bf  = (const float*)d_in[8];
    float* out = (float*)d_out;

    unsigned short* wsHi = (unsigned short*)d_ws;          // 458752 B
    float* wsBias = (float*)(wsHi + FRAG_ELEMS);           // 7168 B (total 465920)

    const int n = in_sizes[0] / 3;                          // 200000
    prep_kernel<<<896, 256, 0, stream>>>(rw1, rw2, rb1, rb2, wsHi, wsBias);
    const int grid = (n + 127) / 128;
    siren_mfma<<<grid, BT, 0, stream>>>(x, w0, b0, wsBias, wf, bf,
                                        (const u4v*)wsHi, out, n);
}

// Round 21
// 205.012 us; speedup vs baseline: 1.7363x; 1.0017x over previous
//
#include <hip/hip_runtime.h>

// Neurcomp / SIREN MLP inference — round 27: r24 (champion, official 205us) +
// 2-deep weight prefetch (3 rotating buffers).
// r25/r26 post-mortem: bf16 LDS staging failed twice (absmax 0.13/0.19) with
// layout proven identical to r24 by element algebra, fences + native stores +
// may_alias applied — mechanism unidentified; branch abandoned per discipline.
// r24 residual: 33% stall at 2 waves/SIMD. The 1-deep ping-pong was sized in
// r14 when t-blocks were ~3x longer; now (8 MFMAs ~128cy) one tile ahead no
// longer covers the ~200-250cy L2 weight latency. VGPR 96 of 256 budget ->
// deepen to 2 tiles ahead: buffers a/b/c (+20 regs). Pure scheduling change on
// the PROVEN r24 dataflow (fp32 f4v LDS staging, XOR swizzle, PKH-on-read,
// single-term MFMA) -> absmax must read exactly 1.220703e-3 (tripwire).
// Layouts (learn_hip m89/m120, r6/r8-verified): A[m=lane&15][k=(lane>>4)*8+j],
// B[k=(lane>>4)*8+j][n=lane&15], D row=(lane>>4)*4+reg, col=lane&15.

typedef unsigned int u32;
typedef short s8v __attribute__((ext_vector_type(8)));   // 8 bf16 (bits)
typedef float f4v __attribute__((ext_vector_type(4)));
typedef u32   u4v __attribute__((ext_vector_type(4)));

constexpr float OMEGA = 30.0f;
constexpr float KREV = 4.7746482946f;  // OMEGA / (2*pi)
constexpr int HID = 128, NRES = 7, BT = 256;
constexpr int WROW = 136;              // dwords per LDS row: 32 b128-blocks + pad
constexpr int WAVE_LDS = 32 * WROW;    // 4352 dwords per wave (32 rows)
constexpr int FRAG_ELEMS = 14 * 16384; // bf16 elems in the weight-frag array

__device__ __forceinline__ float sin_om(float z) {      // first layer only
    float r = z * (OMEGA * 0.15915494309189535f);
    return __builtin_amdgcn_sinf(__builtin_amdgcn_fractf(r));
}
__device__ __forceinline__ float sinrev(float r) {      // input in revolutions
    return __builtin_amdgcn_sinf(__builtin_amdgcn_fractf(r));
}
__device__ __forceinline__ f4v mfma16(s8v a, s8v b, f4v c) {
    return __builtin_amdgcn_mfma_f32_16x16x32_bf16(a, b, c, 0, 0, 0);
}
__device__ __forceinline__ u32 fu(float f) { return __builtin_bit_cast(u32, f); }
__device__ __forceinline__ s8v bc(u4v v) { return __builtin_bit_cast(s8v, v); }
// RTN pack: low16 = bf16(a), high16 = bf16(b)  (v_cvt_pk_bf16_f32, T12 recipe)
__device__ __forceinline__ u32 pkrtn(float a, float b) {
    u32 r;
    asm("v_cvt_pk_bf16_f32 %0, %1, %2" : "=v"(r) : "v"(a), "v"(b));
    return r;
}

// 8 fp32 (frag elem order j=0..7) -> single bf16 s8v via RTN (4 cvt_pk).
#define PKH(e0,e1,e2,e3,e4,e5,e6,e7, FH_) { \
    u4v h_; \
    h_.x = pkrtn(e0, e1); \
    h_.y = pkrtn(e2, e3); \
    h_.z = pkrtn(e4, e5); \
    h_.w = pkrtn(e6, e7); \
    FH_ = __builtin_bit_cast(s8v, h_); }

// h (D-layout regs, feature 16nt+4q+reg at point-row) -> LDS, b128 swizzled.
#define WH(mt,nt) { \
    f4v hv_; hv_.x = H_##mt##_##nt##_0; hv_.y = H_##mt##_##nt##_1; \
    hv_.z = H_##mt##_##nt##_2; hv_.w = H_##mt##_##nt##_3; \
    *(f4v*)&buf[(mt ? rowbase1 : rowbase0) + ((((nt)*4 + q) ^ lnk) << 2)] = hv_; }

// LDS -> B-fragment (single bf16, RTN on read).
#define RS(mt,kc) { \
    const int rb_ = mt ? rowbase1 : rowbase0; \
    f4v u_ = *(const f4v*)&buf[rb_ + ((((kc)*8 + q*2    ) ^ lnk) << 2)]; \
    f4v v_ = *(const f4v*)&buf[rb_ + ((((kc)*8 + q*2 + 1) ^ lnk) << 2)]; \
    PKH(u_.x, u_.y, u_.z, u_.w, v_.x, v_.y, v_.z, v_.w, FH##mt##kc) }

// prefetch weight tile (RTN bf16, single array) + pre-scaled bias — pure loads.
#define PF(S, fbv, bp) { \
    g##S##0 = whi[fbv]; g##S##1 = whi[(fbv)+64]; \
    g##S##2 = whi[(fbv)+128]; g##S##3 = whi[(fbv)+192]; \
    cv##S = *(const f4v*)(bp); }

// 8 MFMAs consuming buffer S — FOUR independent chains (2 each), round-robin,
// s_setprio around the cluster (T5). One term per kc: Wb*Hb.
#define MMB4(S) { \
    s8v h0_=bc(g##S##0), h1_=bc(g##S##1), h2_=bc(g##S##2), h3_=bc(g##S##3); \
    __builtin_amdgcn_s_setprio(1); \
    c0  = mfma16(h0_, FH00, c0 ); c1  = mfma16(h0_, FH10, c1 ); \
    c0b = mfma16(h2_, FH02, c0b); c1b = mfma16(h2_, FH12, c1b); \
    c0  = mfma16(h1_, FH01, c0 ); c1  = mfma16(h1_, FH11, c1 ); \
    c0b = mfma16(h3_, FH03, c0b); c1b = mfma16(h3_, FH13, c1b); \
    __builtin_amdgcn_s_setprio(0); \
    c0 += c0b; c1 += c1b; }

// mm1 step t consuming buffer S: s1 = sin(acc_rev), staged to LDS (fp32)
#define S1(t, S) { \
    f4v c0 = cv##S; f4v c1 = c0; \
    f4v c0b = {0.f, 0.f, 0.f, 0.f}; f4v c1b = c0b; \
    MMB4(S) \
    f4v s0v, s1v; \
    s0v.x = sinrev(c0.x); s0v.y = sinrev(c0.y); \
    s0v.z = sinrev(c0.z); s0v.w = sinrev(c0.w); \
    s1v.x = sinrev(c1.x); s1v.y = sinrev(c1.y); \
    s1v.z = sinrev(c1.z); s1v.w = sinrev(c1.w); \
    const int bo_ = (((t)*4 + q) ^ lnk) << 2; \
    *(f4v*)&buf[rowbase0 + bo_] = s0v; \
    *(f4v*)&buf[rowbase1 + bo_] = s1v; }

// mm2 step t consuming buffer S: epilogue h += s2 (last-layer 0.5 in head)
#define S2(t, S) { \
    f4v c0 = cv##S; f4v c1 = c0; \
    f4v c0b = {0.f, 0.f, 0.f, 0.f}; f4v c1b = c0b; \
    MMB4(S) \
    H_0_##t##_0 += sinrev(c0.x); H_0_##t##_1 += sinrev(c0.y); \
    H_0_##t##_2 += sinrev(c0.z); H_0_##t##_3 += sinrev(c0.w); \
    H_1_##t##_0 += sinrev(c1.x); H_1_##t##_1 += sinrev(c1.y); \
    H_1_##t##_2 += sinrev(c1.z); H_1_##t##_3 += sinrev(c1.w); }

// ---- repetition lists ----
#define LNT8(M) M(0) M(1) M(2) M(3) M(4) M(5) M(6) M(7)
#define LW16(M) M(0,0) M(0,1) M(0,2) M(0,3) M(0,4) M(0,5) M(0,6) M(0,7) \
                M(1,0) M(1,1) M(1,2) M(1,3) M(1,4) M(1,5) M(1,6) M(1,7)
#define LH64(M) \
  M(0,0,0) M(0,0,1) M(0,0,2) M(0,0,3) M(0,1,0) M(0,1,1) M(0,1,2) M(0,1,3) \
  M(0,2,0) M(0,2,1) M(0,2,2) M(0,2,3) M(0,3,0) M(0,3,1) M(0,3,2) M(0,3,3) \
  M(0,4,0) M(0,4,1) M(0,4,2) M(0,4,3) M(0,5,0) M(0,5,1) M(0,5,2) M(0,5,3) \
  M(0,6,0) M(0,6,1) M(0,6,2) M(0,6,3) M(0,7,0) M(0,7,1) M(0,7,2) M(0,7,3) \
  M(1,0,0) M(1,0,1) M(1,0,2) M(1,0,3) M(1,1,0) M(1,1,1) M(1,1,2) M(1,1,3) \
  M(1,2,0) M(1,2,1) M(1,2,2) M(1,2,3) M(1,3,0) M(1,3,1) M(1,3,2) M(1,3,3) \
  M(1,4,0) M(1,4,1) M(1,4,2) M(1,4,3) M(1,5,0) M(1,5,1) M(1,5,2) M(1,5,3) \
  M(1,6,0) M(1,6,1) M(1,6,2) M(1,6,3) M(1,7,0) M(1,7,1) M(1,7,2) M(1,7,3)

#define DH(mt,nt,reg) float H_##mt##_##nt##_##reg;

// first layer (unscaled w0 -> sin_om keeps the omega multiply)
#define F0(nt) { \
    f4v wa_ = *(const f4v*)(w0p + nt*48 + q*12); \
    f4v wb_ = *(const f4v*)(w0p + nt*48 + q*12 + 4); \
    f4v wc_ = *(const f4v*)(w0p + nt*48 + q*12 + 8); \
    f4v bb_ = *(const f4v*)(b0p + nt*16 + q4); \
    H_0_##nt##_0 = sin_om(fmaf(wa_.x, X0, fmaf(wa_.y, Y0, fmaf(wa_.z, Z0, bb_.x)))); \
    H_0_##nt##_1 = sin_om(fmaf(wa_.w, X0, fmaf(wb_.x, Y0, fmaf(wb_.y, Z0, bb_.y)))); \
    H_0_##nt##_2 = sin_om(fmaf(wb_.z, X0, fmaf(wb_.w, Y0, fmaf(wc_.x, Z0, bb_.z)))); \
    H_0_##nt##_3 = sin_om(fmaf(wc_.y, X0, fmaf(wc_.z, Y0, fmaf(wc_.w, Z0, bb_.w)))); \
    H_1_##nt##_0 = sin_om(fmaf(wa_.x, X1, fmaf(wa_.y, Y1, fmaf(wa_.z, Z1, bb_.x)))); \
    H_1_##nt##_1 = sin_om(fmaf(wa_.w, X1, fmaf(wb_.x, Y1, fmaf(wb_.y, Z1, bb_.y)))); \
    H_1_##nt##_2 = sin_om(fmaf(wb_.z, X1, fmaf(wb_.w, Y1, fmaf(wc_.x, Z1, bb_.z)))); \
    H_1_##nt##_3 = sin_om(fmaf(wc_.y, X1, fmaf(wc_.z, Y1, fmaf(wc_.w, Z1, bb_.w)))); }

// final head partials
#define HF(nt) { f4v wf_ = *(const f4v*)(wfp + nt*16 + q4); \
    P0 = fmaf(wf_.x, H_0_##nt##_0, fmaf(wf_.y, H_0_##nt##_1, \
         fmaf(wf_.z, H_0_##nt##_2, fmaf(wf_.w, H_0_##nt##_3, P0)))); \
    P1 = fmaf(wf_.x, H_1_##nt##_0, fmaf(wf_.y, H_1_##nt##_1, \
         fmaf(wf_.z, H_1_##nt##_2, fmaf(wf_.w, H_1_##nt##_3, P1)))); }

// ---- weight prep: 1 element/thread, coalesced; RTN-even bf16 (single array)
// + KREV-scaled bias tail (unchanged from r23/r24).
__global__ void prep_kernel(const float* __restrict__ rw1,
                            const float* __restrict__ rw2,
                            const float* __restrict__ rb1,
                            const float* __restrict__ rb2,
                            unsigned short* __restrict__ wsHi,
                            float* __restrict__ wsBias) {
    int e = blockIdx.x * 256 + threadIdx.x;       // 0 .. 229375
    int j = e & 7, lane = (e >> 3) & 63, kc = (e >> 9) & 3;
    int t = (e >> 11) & 7, L = e >> 14;
    int i = L >> 1;
    bool isW1 = ((L & 1) == 0);
    const float* W = (isW1 ? rw1 : rw2) + i * HID * HID;
    float sc = ((isW1 && i > 0) ? 0.5f : 1.0f) * KREV;   // wgt1 + omega/2pi fold
    int n = t * 16 + (lane & 15);                  // output feature
    int k0 = kc * 32 + (lane >> 4) * 8;            // input feature base
    float w = W[n * HID + k0 + j] * sc;
    u32 b = __builtin_bit_cast(u32, w);
    u32 r = b + 0x7fffu + ((b >> 16) & 1u);        // round-to-nearest-even bf16
    wsHi[e] = (unsigned short)(r >> 16);
    if (e < 14 * HID) {                            // scaled biases: layer Lb, feat f
        int Lb = e >> 7, f = e & 127;
        int li = Lb >> 1;
        float bv = ((Lb & 1) == 0 ? rb1[li * HID + f] : rb2[li * HID + f]);
        wsBias[e] = bv * KREV;
    }
}

__global__ void __launch_bounds__(BT)
__attribute__((amdgpu_waves_per_eu(2, 2)))
siren_mfma(const float* __restrict__ x,
           const float* __restrict__ w0p, const float* __restrict__ b0p,
           const float* __restrict__ bwp,      // pre-scaled biases (d_ws tail)
           const float* __restrict__ wfp, const float* __restrict__ bfp,
           const u4v* __restrict__ whi,
           float* __restrict__ out, int NP)
{
    __shared__ float buf[4 * WAVE_LDS];            // 69632 B, wave-private staging

    const int tid = threadIdx.x;
    const int wv = tid >> 6, lane = tid & 63;
    const int ln = lane & 15, q = lane >> 4;
    const int q4 = q * 4;
    const int lnk = ln & 7;                        // LDS XOR-swizzle key (per row)
    const int rowbase0 = wv * WAVE_LDS + ln * WROW;        // mt0 row (point = ln)
    const int rowbase1 = rowbase0 + 16 * WROW;             // mt1 row (point = 16+ln)
    const int base_pt = blockIdx.x * 128 + wv * 32;

    // ---- first SineLayer, feature-major H
    LH64(DH)
    {
        int p0_ = base_pt + ln;      int i0_ = p0_ < NP ? p0_ : NP - 1;
        int p1_ = base_pt + 16 + ln; int i1_ = p1_ < NP ? p1_ : NP - 1;
        float X0 = x[3*i0_], Y0 = x[3*i0_+1], Z0 = x[3*i0_+2];
        float X1 = x[3*i1_], Y1 = x[3*i1_+1], Z1 = x[3*i1_+2];
        LNT8(F0)
    }

    // activation B-fragments (single bf16) for 2 point-tiles x 4 k-chunks
    s8v FH00, FH01, FH02, FH03, FH10, FH11, FH12, FH13;

    // THREE rotating prefetch buffers (2-deep pipeline)
    u4v ga0, ga1, ga2, ga3;
    u4v gb0, gb1, gb2, gb3;
    u4v gc0, gc1, gc2, gc3;
    f4v cva, cvb, cvc;

    for (int i = 0; i < NRES; ++i) {
        const int fb1 = (2*i) * 2048 + lane, fb2 = (2*i+1) * 2048 + lane;
        const float* __restrict__ B1l = bwp + (2*i) * HID;
        const float* __restrict__ B2l = bwp + (2*i+1) * HID;

        // prologue: prefetch T0,T1 under the h staging phase
        PF(a, fb1,       B1l + q4)
        PF(b, fb1 + 256, B1l + 16 + q4)

        // h (D-layout) -> LDS -> B-fragments (swizzled b128 round-trip)
        LW16(WH)
        RS(0,0) RS(0,1) RS(0,2) RS(0,3)
        RS(1,0) RS(1,1) RS(1,2) RS(1,3)

        // ---- matmul1 -> s1; prefetch T(k+2) before consuming T(k)
        PF(c, fb1 + 512,  B1l + 32 + q4)   S1(0, a)
        PF(a, fb1 + 768,  B1l + 48 + q4)   S1(1, b)
        PF(b, fb1 + 1024, B1l + 64 + q4)   S1(2, c)
        PF(c, fb1 + 1280, B1l + 80 + q4)   S1(3, a)
        PF(a, fb1 + 1536, B1l + 96 + q4)   S1(4, b)
        PF(b, fb1 + 1792, B1l + 112 + q4)  S1(5, c)
        PF(c, fb2,        B2l + q4)        S1(6, a)   // T8 = mm2 t0
        PF(a, fb2 + 256,  B2l + 16 + q4)   S1(7, b)   // T9 = mm2 t1

        // s1 -> fragments (RTN on read)
        RS(0,0) RS(0,1) RS(0,2) RS(0,3)
        RS(1,0) RS(1,1) RS(1,2) RS(1,3)

        // ---- matmul2 -> s2; epilogue h += s2
        PF(b, fb2 + 512,  B2l + 32 + q4)   S2(0, c)
        PF(c, fb2 + 768,  B2l + 48 + q4)   S2(1, a)
        PF(a, fb2 + 1024, B2l + 64 + q4)   S2(2, b)
        PF(b, fb2 + 1280, B2l + 80 + q4)   S2(3, c)
        PF(c, fb2 + 1536, B2l + 96 + q4)   S2(4, a)
        PF(a, fb2 + 1792, B2l + 112 + q4)  S2(5, b)
        S2(6, c)
        S2(7, a)
    }

    // ---- final linear head
    float P0 = 0.f, P1 = 0.f;
    LNT8(HF)
    P0 += __shfl_xor(P0, 16); P0 += __shfl_xor(P0, 32);
    P1 += __shfl_xor(P1, 16); P1 += __shfl_xor(P1, 32);
    const float bf0 = bfp[0];
    if (q == 0) {
        int p0_ = base_pt + ln;
        if (p0_ < NP) out[p0_] = fmaf(P0, 0.5f, bf0);      // 0.5 = last-layer wgt2
        int p1_ = base_pt + 16 + ln;
        if (p1_ < NP) out[p1_] = fmaf(P1, 0.5f, bf0);
    }
}

extern "C" void kernel_launch(void* const* d_in, const int* in_sizes, int n_in,
                              void* d_out, int out_size, void* d_ws, size_t ws_size,
                              hipStream_t stream) {
    const float* x   = (const float*)d_in[0];
    const float* w0  = (const float*)d_in[1];
    const float* b0  = (const float*)d_in[2];
    const float* rw1 = (const float*)d_in[3];
    const float* rb1 = (const float*)d_in[4];
    const float* rw2 = (const float*)d_in[5];
    const float* rb2 = (const float*)d_in[6];
    const float* wf  = (const float*)d_in[7];
    const float* bf  = (const float*)d_in[8];
    float* out = (float*)d_out;

    unsigned short* wsHi = (unsigned short*)d_ws;          // 458752 B
    float* wsBias = (float*)(wsHi + FRAG_ELEMS);           // 7168 B (total 465920)

    const int n = in_sizes[0] / 3;                          // 200000
    prep_kernel<<<896, 256, 0, stream>>>(rw1, rw2, rb1, rb2, wsHi, wsBias);
    const int grid = (n + 127) / 128;
    siren_mfma<<<grid, BT, 0, stream>>>(x, w0, b0, wsBias, wf, bf,
                                        (const u4v*)wsHi, out, n);
}